// Round 10
// baseline (48.608 us; speedup 1.0000x reference)
//
#include <hip/hip_runtime.h>

// Problem constants (B, C, O, K, H, W) = (8, 64, 64, 3, 128, 128)
#define NTAP 9
#define C_DIM 64
#define O_DIM 64
#define HW 128
#define HP 130   // padded spatial extent (one halo pixel each side)

typedef short s16x8 __attribute__((ext_vector_type(8)));
typedef float f32x16 __attribute__((ext_vector_type(16)));

__device__ __forceinline__ unsigned short f2bf(float x) {
    unsigned int u = __float_as_uint(x);
    unsigned int r = (u + 0x7fffu + ((u >> 16) & 1u)) >> 16;
    return (unsigned short)r;
}

// async global->LDS, 16B per lane; LDS dest is wave-uniform base + lane*16
__device__ __forceinline__ void gl_lds16(const unsigned short* g, unsigned short* l) {
    __builtin_amdgcn_global_load_lds(
        (const __attribute__((address_space(1))) unsigned short*)g,
        (__attribute__((address_space(3))) unsigned short*)l, 16, 0, 0);
}

// ---------------------------------------------------------------------------
// Pre-kernel A: W [C=64][3][3][O=64] f32 -> fragment-major bf16 (72KB).
// Fragment F = ((tap*4 + s)*2 + m)*64 + lane, element e:
//   c = 16*s + 8*(lane>>5) + e,   o = 32*m + (lane&31)
// Same (lane>>5, e) -> k-slot mapping is used for the feat (B) operand, so the
// contraction is correct under any hardware k-slot permutation.
// ---------------------------------------------------------------------------
__global__ void swizzle_W_kernel(const float* __restrict__ W,
                                 unsigned short* __restrict__ Wf) {
    int idx = blockIdx.x * 256 + threadIdx.x;
    if (idx >= NTAP * 4 * 2 * 64 * 8) return;
    int e    = idx & 7;
    int lane = (idx >> 3) & 63;
    int m    = (idx >> 9) & 1;
    int s    = (idx >> 10) & 3;
    int tap  = idx >> 12;
    int c = s * 16 + ((lane >> 5) << 3) + e;
    int o = (m << 5) + (lane & 31);
    Wf[idx] = f2bf(W[c * 576 + tap * 64 + o]);
}

// ---------------------------------------------------------------------------
// Pre-kernel B: feat [8][64][128][128] f32 -> featT [8][130][130][64] bf16,
// channel-last, zero-padded halo ring, octet-swizzled: the c-octet `oct` of
// pixel (hp,wp) is stored at 16B slot (oct ^ (wp&7)). One block per (b, hp).
// ---------------------------------------------------------------------------
__global__ __launch_bounds__(256) void transpose_feat_kernel(
    const float* __restrict__ feat, unsigned short* __restrict__ featT)
{
    __shared__ unsigned short lds_t[C_DIM][134];   // [c][w], odd-dword stride

    const int bid = blockIdx.x;               // 0..1039, XCD x owns batch x
    const int b   = bid & 7;
    const int hp  = bid >> 3;                 // 0..129
    const int hr  = hp - 1;
    const int tid = threadIdx.x;
    const bool rowv = (hr >= 0) && (hr < HW);

    if (rowv) {
        const int wq = tid & 31;               // w = 4*wq (coalesced)
        const int c0 = tid >> 5;               // c = c0 + 8*i
        #pragma unroll
        for (int i = 0; i < 8; ++i) {
            const int c = c0 + 8 * i;
            float4 v = *(const float4*)&feat[(((size_t)(b * C_DIM + c)) * HW + hr) * HW + 4 * wq];
            unsigned int lo = (unsigned int)f2bf(v.x) | ((unsigned int)f2bf(v.y) << 16);
            unsigned int hi = (unsigned int)f2bf(v.z) | ((unsigned int)f2bf(v.w) << 16);
            *(unsigned int*)&lds_t[c][4 * wq]     = lo;
            *(unsigned int*)&lds_t[c][4 * wq + 2] = hi;
        }
    }
    __syncthreads();

    for (int u = tid; u < HP * 8; u += 256) {  // 1040 units = 130 wp x 8 octets
        const int wp  = u >> 3;
        const int oct = u & 7;
        s16x8 pk = {0, 0, 0, 0, 0, 0, 0, 0};
        if (rowv && wp >= 1 && wp <= HW) {
            #pragma unroll
            for (int e = 0; e < 8; ++e) pk[e] = (short)lds_t[oct * 8 + e][wp - 1];
        }
        const int slot = oct ^ (wp & 7);
        *(s16x8*)&featT[((((size_t)b * HP) + hp) * HP + wp) * 64 + slot * 8] = pk;
    }
}

// ---------------------------------------------------------------------------
// Main kernel: one block per (batch, h-PAIR, 64-w half). 256 threads = 4 waves.
// Stage: each wave issues 9 global_load_lds_dwordx4 covering one padded row
// segment featT[b][h0+wave][w0 .. w0+71][*] (9216B contiguous) -> LDS verbatim
// (swizzle pre-applied in global). Zero staging VGPRs / pack VALU.
// Compute: wave (m = o-half, pg = w-32-group) runs TWO 32px x 32o chains
// (rows h0, h0+1) sharing every A-fragment. LDS read slot = (2s+g) ^ (wi&7).
// ---------------------------------------------------------------------------
__global__ __launch_bounds__(256, 4) void dyconv_kernel(
    const unsigned short* __restrict__ featT, const float* __restrict__ tm,
    const unsigned short* __restrict__ Wf, float* __restrict__ out)
{
    __shared__ __align__(16) unsigned short feat_lds[4][72][64];  // 36.9KB

    const int flat  = blockIdx.x;              // 0..1023, XCD x owns batch x
    const int b     = flat & 7;
    const int inner = flat >> 3;               // 0..127
    const int h0    = (inner >> 1) * 2;        // 0,2,..,126
    const int w0    = (inner & 1) << 6;        // 0 or 64

    const int tid  = threadIdx.x;
    const int lane = tid & 63;
    const int wave = tid >> 6;                 // 0..3
    const int m    = wave >> 1;                // o-half
    const int pg   = wave & 1;                 // w 32-group
    const int g    = lane >> 5;                // k-slot half
    const int c31  = lane & 31;
    const int pw   = pg * 32 + c31;            // pixel w-offset 0..63
    const int wout = w0 + pw;

    // ---- async stage: wave r DMAs padded row hp = h0+r, wp in [w0, w0+72) ----
    {
        const unsigned short* seg =
            featT + ((((size_t)b * HP) + h0 + wave) * HP + w0) * 64;
        unsigned short* lrow = &feat_lds[wave][0][0];
        #pragma unroll
        for (int k = 0; k < 9; ++k)
            gl_lds16(seg + k * 512 + lane * 8, lrow + k * 512);
    }

    // tm prefetch (vmem in flight across the barrier)
    float tmr0[NTAP], tmr1[NTAP];
    #pragma unroll
    for (int t = 0; t < NTAP; ++t) {
        const float* tp = tm + ((size_t)(b * NTAP + t)) * (HW * HW)
                        + (size_t)h0 * HW + wout;
        tmr0[t] = tp[0];
        tmr1[t] = tp[HW];
    }

    __syncthreads();   // drains vmcnt -> LDS writes visible

    const s16x8* __restrict__ Wf8 = (const s16x8*)Wf;

    f32x16 acc0 = {0,0,0,0,0,0,0,0,0,0,0,0,0,0,0,0};
    f32x16 acc1 = acc0;

    __builtin_amdgcn_s_setprio(1);
    #pragma unroll
    for (int tap = 0; tap < NTAP; ++tap) {
        const int di = tap / 3;
        const int dj = tap % 3;
        const int wi = pw + dj;                // 0..65
        const int sw = wi & 7;                 // octet swizzle key
        f32x16 pa0 = {0,0,0,0,0,0,0,0,0,0,0,0,0,0,0,0};
        f32x16 pa1 = pa0;
        #pragma unroll
        for (int s = 0; s < 4; ++s) {
            const int slot = (2 * s + g) ^ sw;
            s16x8 bf0 = *(const s16x8*)&feat_lds[di    ][wi][slot * 8];
            s16x8 bf1 = *(const s16x8*)&feat_lds[di + 1][wi][slot * 8];
            s16x8 a   = Wf8[((tap * 4 + s) * 2 + m) * 64 + lane];  // shared A
            pa0 = __builtin_amdgcn_mfma_f32_32x32x16_bf16(a, bf0, pa0, 0, 0, 0);
            pa1 = __builtin_amdgcn_mfma_f32_32x32x16_bf16(a, bf1, pa1, 0, 0, 0);
        }
        const float tv0 = tmr0[tap];
        const float tv1 = tmr1[tap];
        #pragma unroll
        for (int r = 0; r < 16; ++r) {
            acc0[r] = fmaf(tv0, pa0[r], acc0[r]);
            acc1[r] = fmaf(tv1, pa1[r], acc1[r]);
        }
    }
    __builtin_amdgcn_s_setprio(0);

    // ---- store rows h0, h0+1: D (32x32): col = c31, o = (r&3)+8*(r>>2)+4g+32m
    float* op = out + ((size_t)b * O_DIM) * (HW * HW) + (size_t)h0 * HW + wout;
    #pragma unroll
    for (int r = 0; r < 16; ++r) {
        const int o = (r & 3) + ((r >> 2) << 3) + (g << 2) + (m << 5);
        op[(size_t)o * (HW * HW)]      = acc0[r];
        op[(size_t)o * (HW * HW) + HW] = acc1[r];
    }
}

extern "C" void kernel_launch(void* const* d_in, const int* in_sizes, int n_in,
                              void* d_out, int out_size, void* d_ws, size_t ws_size,
                              hipStream_t stream) {
    const float* feat = (const float*)d_in[0];   // [8,64,128,128] f32
    const float* tm   = (const float*)d_in[1];   // [8,9,16384]    f32
    const float* W    = (const float*)d_in[2];   // [64,3,3,64]    f32
    float* out        = (float*)d_out;           // [8,64,128,128] f32

    // ws layout: featT [0, 17305600) bf16; Wf [17305600, 17379328)
    unsigned short* featT = (unsigned short*)d_ws;
    unsigned short* Wf    = (unsigned short*)((char*)d_ws + 17305600);

    swizzle_W_kernel<<<dim3(144), dim3(256), 0, stream>>>(W, Wf);
    transpose_feat_kernel<<<dim3(8 * HP), dim3(256), 0, stream>>>(feat, featT);
    dyconv_kernel<<<dim3(1024), dim3(256), 0, stream>>>(featT, tm, Wf, out);
}

// Round 11
// 38.493 us; speedup vs baseline: 1.2628x; 1.2628x over previous
//
#include <hip/hip_runtime.h>

// Problem constants (B, C, O, K, H, W) = (8, 64, 64, 3, 128, 128)
#define NTAP 9
#define C_DIM 64
#define O_DIM 64
#define HW 128

typedef short s16x8 __attribute__((ext_vector_type(8)));
typedef float f32x16 __attribute__((ext_vector_type(16)));

__device__ __forceinline__ unsigned short f2bf(float x) {
    unsigned int u = __float_as_uint(x);
    unsigned int r = (u + 0x7fffu + ((u >> 16) & 1u)) >> 16;
    return (unsigned short)r;
}

// ---------------------------------------------------------------------------
// Pre-kernel: W [C=64][3][3][O=64] f32 -> fragment-major bf16 (d_ws, 72KB).
// Fragment F = ((tap*4 + s)*2 + m)*64 + lane, element e:
//   c = 16*s + 8*(lane>>5) + e,   o = 32*m + (lane&31)
// Same (lane>>5, e) -> k-slot mapping is used for the feat (B) operand, so the
// contraction is correct under any hardware k-slot permutation.
// ---------------------------------------------------------------------------
__global__ void swizzle_W_kernel(const float* __restrict__ W,
                                 unsigned short* __restrict__ Wf) {
    int idx = blockIdx.x * 256 + threadIdx.x;
    if (idx >= NTAP * 4 * 2 * 64 * 8) return;
    int e    = idx & 7;
    int lane = (idx >> 3) & 63;
    int m    = (idx >> 9) & 1;
    int s    = (idx >> 10) & 3;
    int tap  = idx >> 12;
    int c = s * 16 + ((lane >> 5) << 3) + e;
    int o = (m << 5) + (lane & 31);
    Wf[idx] = f2bf(W[c * 576 + tap * 64 + o]);
}

// ---------------------------------------------------------------------------
// Main kernel: one block per (batch, h-PAIR, 64-w half). 512 threads = 8 waves.
// LDS window: 4 rows x 66 wi x 64 c bf16, tight 128B rows, octet-XOR layout:
//   c-octet `oct` of column wi lives at 16B slot (oct ^ (wi&7)).
// Read pattern (lane -> slot = (2s+g)^(wi&7), wi = pw+dj contiguous per lane)
// reproduces the canonical conflict-free 4*lane%32 bank multiset.
// Staging: 576 inline units (4r x 18q x 8oct): 8 coalesced float4 loads ->
// pack -> up to 4 ds_write_b128. One unit per thread (+64 spread 8/wave).
// Compute: wave = (hrow, m, pg): ONE 32px x 32o chain, 36 MFMA, tm-fold.
// ---------------------------------------------------------------------------
__global__ __launch_bounds__(512, 4) void dyconv_kernel(
    const float* __restrict__ feat, const float* __restrict__ tm,
    const unsigned short* __restrict__ Wf, float* __restrict__ out)
{
    __shared__ __align__(16) unsigned short feat_lds[4][66][64];  // 33792 B

    // bijective XCD swizzle: XCD x owns batch x; h-neighbors adjacent in time
    const int flat  = blockIdx.x;              // 0..1023
    const int b     = flat & 7;
    const int inner = flat >> 3;               // 0..127
    const int h0    = (inner >> 1) * 2;        // 0,2,..,126
    const int w0    = (inner & 1) << 6;        // 0 or 64

    const int tid  = threadIdx.x;
    const int lane = tid & 63;
    const int wave = tid >> 6;                 // 0..7
    const int hrow = (wave >> 2) & 1;          // output row h0+hrow
    const int m    = (wave >> 1) & 1;          // o-half
    const int pg   = wave & 1;                 // w 32-group
    const int g    = lane >> 5;                // k-slot half
    const int c31  = lane & 31;
    const int pw   = pg * 32 + c31;            // pixel w-offset 0..63
    const int wout = w0 + pw;
    const int hout = h0 + hrow;

    // ---- staging: unit U = ((r*18)+q)*8 + oct ----
    auto do_unit = [&](int U) {
        const int oct = U & 7;
        const int t6  = U >> 3;                // 0..71
        const int q   = t6 % 18;               // w-quad: wb = w0-4+4q
        const int r   = t6 / 18;               // input row (hr = h0-1+r)
        const int hr  = h0 - 1 + r;
        const int wb  = w0 - 4 + 4 * q;
        const bool ld = (hr >= 0) && (hr < HW) && (wb >= 0) && (wb <= HW - 4);
        const float* src = feat + (((size_t)(b * C_DIM + oct * 8)) * HW + hr) * HW + wb;
        float4 v[8];
        #pragma unroll
        for (int j = 0; j < 8; ++j)
            v[j] = ld ? *(const float4*)(src + (size_t)j * (HW * HW))
                      : float4{0.f, 0.f, 0.f, 0.f};
        #pragma unroll
        for (int i = 0; i < 4; ++i) {
            const int wi = 4 * q - 3 + i;      // window index = w_in - (w0-1)
            if (wi >= 0 && wi <= 65) {
                const int slot = oct ^ (wi & 7);
                s16x8 pk;
                #pragma unroll
                for (int j = 0; j < 8; ++j) {
                    const float* vf = (const float*)&v[j];
                    pk[j] = (short)f2bf(vf[i]);
                }
                *(s16x8*)&feat_lds[r][wi][slot * 8] = pk;
            }
        }
    };

    // tm prefetch (independent; overlaps staging latency, drained by barrier)
    float tmr[NTAP];
    #pragma unroll
    for (int t = 0; t < NTAP; ++t)
        tmr[t] = tm[((size_t)(b * NTAP + t)) * (HW * HW) + (size_t)hout * HW + wout];

    do_unit(tid);                              // units 0..511
    if ((tid & 7) == 0) do_unit(512 + (tid >> 3));   // units 512..575, 8/wave

    __syncthreads();

    const s16x8* __restrict__ Wf8 = (const s16x8*)Wf;

    f32x16 acc = {0,0,0,0,0,0,0,0,0,0,0,0,0,0,0,0};

    __builtin_amdgcn_s_setprio(1);
    #pragma unroll
    for (int tap = 0; tap < NTAP; ++tap) {
        const int di = tap / 3;
        const int dj = tap % 3;
        const int wi = pw + dj;                // 0..65, contiguous across lanes
        const int sw = wi & 7;
        f32x16 pa = {0,0,0,0,0,0,0,0,0,0,0,0,0,0,0,0};
        #pragma unroll
        for (int s = 0; s < 4; ++s) {
            const int slot = (2 * s + g) ^ sw;
            s16x8 bf = *(const s16x8*)&feat_lds[hrow + di][wi][slot * 8];
            s16x8 a  = Wf8[((tap * 4 + s) * 2 + m) * 64 + lane];   // L2-hot 16B
            pa = __builtin_amdgcn_mfma_f32_32x32x16_bf16(a, bf, pa, 0, 0, 0);
        }
        const float tv = tmr[tap];
        #pragma unroll
        for (int r = 0; r < 16; ++r)
            acc[r] = fmaf(tv, pa[r], acc[r]);
    }
    __builtin_amdgcn_s_setprio(0);

    // ---- store: D (32x32): col = c31 (pixel), o = (r&3)+8*(r>>2)+4*g+32*m ----
    float* op = out + ((size_t)b * O_DIM) * (HW * HW) + (size_t)hout * HW + wout;
    #pragma unroll
    for (int r = 0; r < 16; ++r) {
        const int o = (r & 3) + ((r >> 2) << 3) + (g << 2) + (m << 5);
        op[(size_t)o * (HW * HW)] = acc[r];
    }
}

extern "C" void kernel_launch(void* const* d_in, const int* in_sizes, int n_in,
                              void* d_out, int out_size, void* d_ws, size_t ws_size,
                              hipStream_t stream) {
    const float* feat = (const float*)d_in[0];   // [8,64,128,128] f32
    const float* tm   = (const float*)d_in[1];   // [8,9,16384]    f32
    const float* W    = (const float*)d_in[2];   // [64,3,3,64]    f32
    float* out        = (float*)d_out;           // [8,64,128,128] f32
    unsigned short* Wf = (unsigned short*)d_ws;  // 73728 B scratch

    swizzle_W_kernel<<<dim3(144), dim3(256), 0, stream>>>(W, Wf);
    dyconv_kernel<<<dim3(1024), dim3(512), 0, stream>>>(feat, tm, Wf, out);
}